// Round 6
// baseline (182.506 us; speedup 1.0000x reference)
//
#include <hip/hip_runtime.h>
#include <cstdint>
#include <cstddef>

#define LN_EPS 1e-5f

typedef __attribute__((ext_vector_type(8))) __bf16 bf16x8;
typedef __attribute__((ext_vector_type(4))) float f32x4;

__device__ __forceinline__ unsigned short f2bf(float f) {
    union { float f; unsigned int u; } v; v.f = f;
    unsigned int u = v.u;
    return (unsigned short)((u + 0x7FFFu + ((u >> 16) & 1u)) >> 16);
}

// tanh-form gelu via sigmoid: x * sigmoid(2*0.7978845608*(x + 0.044715x^3))
__device__ __forceinline__ float gelu_fast(float x) {
    const float x2 = x * x;
    const float p = fmaf(x2, 0.0356774081f, 0.7978845608f);
    const float y = x * p;
    const float e = __expf(-2.f * y);
    const float d = __builtin_amdgcn_rcpf(1.f + e);
    return x * d;
}

// ---------------------------------------------------------------------------
// K1 v3: pair -> seq.  One block per (b,i).  CHUNKED TWO-PASS over the
// 512x128 pair row (4 chunks of 128 rows):
//   pass1: 4 lanes/row compute LN stats + logit + er (6 shuffles/chunk/thread)
//   pass2: fixed-p layout accumulates V from L2-hot chunk, ZERO shuffles.
// Then proj, seq-LN, hi/hj GEMVs. Blocks 0..31 also transpose w2 -> bf16.
// ---------------------------------------------------------------------------
__global__ __launch_bounds__(512) void k1_pair2seq(
    const float* __restrict__ seq, const float* __restrict__ pair,
    const float* __restrict__ ln_p_w, const float* __restrict__ ln_p_b,
    const float* __restrict__ pool_w, const float* __restrict__ pool_b,
    const float* __restrict__ proj_w, const float* __restrict__ proj_b,
    const float* __restrict__ gate_ps, const float* __restrict__ ln_s_w,
    const float* __restrict__ ln_s_b, const float* __restrict__ w1,
    const float* __restrict__ b1, const float* __restrict__ w2,
    float* __restrict__ seq_out, float* __restrict__ hi_out,
    float* __restrict__ hj_out, unsigned short* __restrict__ w2t)
{
    const int bid = blockIdx.x;            // = b*512 + i
    const int tid = threadIdx.x;
    const int w = tid >> 6, lane = tid & 63;

    // folded k0: w2 (128x128 f32 [k][n]) -> w2t bf16 transposed [n][k]
    if (bid < 32) {
        const int idx = bid * 512 + tid;
        const int k = idx >> 7, n = idx & 127;
        w2t[n * 128 + k] = f2bf(w2[idx]);
    }

    __shared__ float pwl_s[128];
    __shared__ float er_s[128];
    __shared__ float wv[16][128];
    __shared__ float redSU[8][2];
    __shared__ float cc[2];
    __shared__ float pooled[128];
    __shared__ float su_s[256];
    __shared__ float sn_s[256];
    __shared__ float redln[8];
    __shared__ float epart[2][256];

    // pwl = ln_p_w * pool_w (elementwise); c1 = sum(pwl); c2 = dot(ln_b,pw)+pb
    if (tid < 128) pwl_s[tid] = ln_p_w[tid] * pool_w[tid];
    __syncthreads();
    if (tid < 64) {
        float t1 = pwl_s[tid] + pwl_s[tid + 64];
        float t2 = ln_p_b[tid] * pool_w[tid] + ln_p_b[tid + 64] * pool_w[tid + 64];
        for (int d = 1; d < 64; d <<= 1) {
            t1 += __shfl_xor(t1, d);
            t2 += __shfl_xor(t2, d);
        }
        if (lane == 0) { cc[0] = t1; cc[1] = t2 + pool_b[0]; }
    }
    __syncthreads();
    const float c1 = cc[0], c2 = cc[1];

    // ---- Phase A: chunked two-pass ----
    const float* prow = pair + (((size_t)bid) << 16);   // bid * 512 * 128
    const int q = tid & 3;             // quarter of a row (pass 1)
    const int r_loc = tid >> 2;        // row within chunk (pass 1)
    const int g = tid >> 5;            // group 0..15 (pass 2)
    const int pq = (tid & 31) * 4;     // fixed p-quad (pass 2)

    float sS = 0.f, sU = 0.f;
    float v0 = 0.f, v1 = 0.f, v2 = 0.f, v3 = 0.f;

    #pragma unroll
    for (int c = 0; c < 4; ++c) {
        // pass 1: rows c*128 .. c*128+127, 4 lanes per row
        {
            const float* rp = prow + ((size_t)(c * 128 + r_loc)) * 128 + q * 32;
            float a1 = 0.f, a2 = 0.f, a3 = 0.f;
            #pragma unroll
            for (int ii = 0; ii < 8; ++ii) {
                const float4 x = *(const float4*)(rp + ii * 4);
                const float4 pw4 = *(const float4*)(pwl_s + q * 32 + ii * 4);
                a1 += x.x + x.y + x.z + x.w;
                a2 = fmaf(x.x, x.x, fmaf(x.y, x.y, fmaf(x.z, x.z, fmaf(x.w, x.w, a2))));
                a3 = fmaf(x.x, pw4.x, fmaf(x.y, pw4.y, fmaf(x.z, pw4.z, fmaf(x.w, pw4.w, a3))));
            }
            a1 += __shfl_xor(a1, 1); a2 += __shfl_xor(a2, 1); a3 += __shfl_xor(a3, 1);
            a1 += __shfl_xor(a1, 2); a2 += __shfl_xor(a2, 2); a3 += __shfl_xor(a3, 2);
            const float mu = a1 * (1.f / 128.f);
            const float var = fmaf(-mu, mu, a2 * (1.f / 128.f));
            const float rstd = rsqrtf(var + LN_EPS);
            const float logit = fmaf(rstd, fmaf(-mu, c1, a3), c2);
            const float e = __expf(logit);
            const float er = e * rstd;
            if (q == 0) {
                er_s[r_loc] = er;
                sS += e;
                sU = fmaf(er, mu, sU);
            }
        }
        __syncthreads();   // er_s ready
        // pass 2: group g accumulates rows c*128 + g*8 .. +8 at fixed p-quad
        {
            const int rb = c * 128 + g * 8;
            #pragma unroll
            for (int k = 0; k < 8; ++k) {
                const float er = er_s[g * 8 + k];
                const float4 x = *(const float4*)(prow + ((size_t)(rb + k)) * 128 + pq);
                v0 = fmaf(er, x.x, v0);
                v1 = fmaf(er, x.y, v1);
                v2 = fmaf(er, x.z, v2);
                v3 = fmaf(er, x.w, v3);
            }
        }
        __syncthreads();   // before er_s overwrite next chunk
    }

    // reduce S,U across block; publish group partial V
    for (int d = 1; d < 64; d <<= 1) {
        sS += __shfl_xor(sS, d);
        sU += __shfl_xor(sU, d);
    }
    if (lane == 0) { redSU[w][0] = sS; redSU[w][1] = sU; }
    {
        float4 vv = { v0, v1, v2, v3 };
        *(float4*)&wv[g][pq] = vv;
    }
    __syncthreads();

    // ---- Phase B: combine ----
    if (tid < 128) {
        float S = 0.f, U = 0.f;
        #pragma unroll
        for (int k = 0; k < 8; ++k) { S += redSU[k][0]; U += redSU[k][1]; }
        float V = 0.f;
        #pragma unroll
        for (int k = 0; k < 16; ++k) V += wv[k][tid];
        pooled[tid] = ln_p_w[tid] * ((V - U) / S) + ln_p_b[tid];
    }
    __syncthreads();

    // ---- Phase C: seq_updated = seq + sig(gate)*(pooled @ proj_w + proj_b)
    float gps = gate_ps[0];
    gps = 1.f / (1.f + __expf(-gps));
    if (tid < 256) {
        float acc = proj_b[tid];
        #pragma unroll 8
        for (int p = 0; p < 128; ++p)
            acc = fmaf(pooled[p], proj_w[p * 256 + tid], acc);
        const size_t so = ((size_t)bid) * 256 + tid;
        const float su = seq[so] + gps * acc;
        seq_out[so] = su;
        su_s[tid] = su;
    }
    __syncthreads();

    // ---- Phase D: LN over D=256 of seq_updated ----
    if (tid < 256) {
        const float x = su_s[tid];
        float s1 = x, s2 = x * x;
        for (int d = 1; d < 64; d <<= 1) {
            s1 += __shfl_xor(s1, d);
            s2 += __shfl_xor(s2, d);
        }
        if (lane == 0) { redln[w * 2] = s1; redln[w * 2 + 1] = s2; }
    }
    __syncthreads();
    if (tid < 256) {
        const float s1 = redln[0] + redln[2] + redln[4] + redln[6];
        const float s2 = redln[1] + redln[3] + redln[5] + redln[7];
        const float mu = s1 * (1.f / 256.f);
        const float var = s2 * (1.f / 256.f) - mu * mu;
        const float rstd = rsqrtf(var + LN_EPS);
        sn_s[tid] = (su_s[tid] - mu) * rstd * ln_s_w[tid] + ln_s_b[tid];
    }
    __syncthreads();

    // ---- Phase E: hi = sn@w1[:256] + b1 ; hj = sn@w1[256:]  (k split x2) ----
    {
        const int outi = tid & 255;            // 0-127: hi, 128-255: hj
        const int kh = tid >> 8;               // k-half
        const int p = outi & 127;
        const int rowbase = (outi < 128 ? 0 : 256) + kh * 128;
        const float* wcol = w1 + rowbase * 128 + p;
        float acc = 0.f;
        #pragma unroll 8
        for (int k = 0; k < 128; ++k)
            acc = fmaf(sn_s[kh * 128 + k], wcol[k * 128], acc);
        epart[kh][outi] = acc;
    }
    __syncthreads();
    if (tid < 256) {
        const int p = tid & 127;
        const float r = epart[0][tid] + epart[1][tid];
        const size_t ho = ((size_t)bid) * 128 + p;
        if (tid < 128) hi_out[ho] = r + b1[p];   // fold b1 into hi
        else           hj_out[ho] = r;
    }
}

// ---------------------------------------------------------------------------
// K2 v4-lean: pair_out = pair + sig(gate)*(gelu(hi + hj) @ w2 + b2)
// One block per (b,i,j-tile of 128), 8 waves x 16 j-rows, swapped MFMA
// operands (lane owns 4 consecutive n-cols of one j-row -> dwordx4 epilogue).
// NO residual prefetch registers: residual loaded inside the epilogue to
// keep VGPR < 96 so 2 blocks/CU stay resident (the v4 regression suspect).
// ---------------------------------------------------------------------------
__global__ __launch_bounds__(512, 4) void k2_seq2pair(
    const float* __restrict__ pair, const float* __restrict__ hi,
    const float* __restrict__ hj, const unsigned short* __restrict__ w2t,
    const float* __restrict__ b2, const float* __restrict__ gate_sp,
    float* __restrict__ pair_out)
{
    const int rbid = 4095 - blockIdx.x;      // reverse of k1's streaming order
    const int jt = rbid & 3;
    const int bi = rbid >> 2;                // b*512 + i
    const int b = rbid >> 11;
    const int tid = threadIdx.x;
    const int w = tid >> 6, lane = tid & 63;
    const int l15 = lane & 15;
    const int kgrp = lane >> 4;

    __shared__ unsigned short hs[128 * 128];    // 32 KB, swizzled [j][p]
    __shared__ unsigned short w2s[128 * 128];   // 32 KB, swizzled [n][k]

    // hi row for this i: each thread only ever needs 4 fixed p's
    const float4 hiv = *(const float4*)(hi + ((size_t)bi) * 128 + (tid & 31) * 4);

    // stage w2^T (bf16) into LDS, swizzled: 4096 ushort4 / 512 threads
    {
        const ushort4* src = (const ushort4*)w2t;
        #pragma unroll
        for (int ii = 0; ii < 8; ++ii) {
            const int flat4 = ii * 512 + tid;
            const int n = flat4 >> 5;
            const int k4 = flat4 & 31;
            const ushort4 vldv = src[flat4];
            const unsigned off = (unsigned)((n * 256 + k4 * 8) ^ ((n & 7) << 4));
            *(ushort4*)((char*)w2s + off) = vldv;
        }
    }

    // build h tile: gelu(hi + hj) -> bf16 LDS, swizzled: 4096 float4 / 512
    const int j0 = jt << 7;
    const float* hjb = hj + ((size_t)(b * 512 + j0)) * 128;
    #pragma unroll
    for (int ii = 0; ii < 8; ++ii) {
        const int flat4 = ii * 512 + tid;
        const int r = flat4 >> 5;
        const int c4 = flat4 & 31;
        const float4 xv = *(const float4*)(hjb + r * 128 + c4 * 4);
        const float h0 = gelu_fast(xv.x + hiv.x);
        const float h1 = gelu_fast(xv.y + hiv.y);
        const float h2 = gelu_fast(xv.z + hiv.z);
        const float h3 = gelu_fast(xv.w + hiv.w);
        ushort4 ov = { f2bf(h0), f2bf(h1), f2bf(h2), f2bf(h3) };
        const unsigned off = (unsigned)((r * 256 + c4 * 8) ^ ((r & 7) << 4));
        *(ushort4*)((char*)hs + off) = ov;
    }
    __syncthreads();

    float gsp = gate_sp[0];
    gsp = 1.f / (1.f + __expf(-gsp));

    const int jrow = w * 16 + l15;                       // this lane's j row

    // MFMA: wave w covers j-rows [w*16, w*16+16) x all 128 n-cols.
    // A = w2 fragment (n on M-axis), B = h fragment (j on N-axis).
    f32x4 acc[8];
    #pragma unroll
    for (int nn = 0; nn < 8; ++nn) acc[nn] = (f32x4){0.f, 0.f, 0.f, 0.f};

    #pragma unroll
    for (int ks = 0; ks < 4; ++ks) {
        const int kb = ks * 32 + kgrp * 8;
        const unsigned hoff = (unsigned)((jrow * 256 + kb * 2) ^ ((jrow & 7) << 4));
        const bf16x8 hf = *(const bf16x8*)((const char*)hs + hoff);
        #pragma unroll
        for (int nn = 0; nn < 8; ++nn) {
            const int nrow = nn * 16 + l15;
            const unsigned woff = (unsigned)((nrow * 256 + kb * 2) ^ ((nrow & 7) << 4));
            const bf16x8 wf = *(const bf16x8*)((const char*)w2s + woff);
            acc[nn] = __builtin_amdgcn_mfma_f32_16x16x32_bf16(wf, hf, acc[nn], 0, 0, 0);
        }
    }

    // epilogue: residual + gate + bias, dwordx4 loads + dwordx4 NT stores
    const size_t rowbase = ((size_t)bi * 512 + j0 + jrow) * 128 + kgrp * 4;
    const float* prsrc = pair + rowbase;
    float* pdst = pair_out + rowbase;
    #pragma unroll
    for (int nn = 0; nn < 8; ++nn) {
        const f32x4 pr = *(const f32x4*)(prsrc + nn * 16);
        const f32x4 bq = *(const f32x4*)(b2 + nn * 16 + kgrp * 4);
        f32x4 val;
        #pragma unroll
        for (int qq = 0; qq < 4; ++qq)
            val[qq] = fmaf(gsp, acc[nn][qq] + bq[qq], pr[qq]);
        __builtin_nontemporal_store(val, (f32x4*)(pdst + nn * 16));
    }
}

// ---------------------------------------------------------------------------
extern "C" void kernel_launch(void* const* d_in, const int* in_sizes, int n_in,
                              void* d_out, int out_size, void* d_ws, size_t ws_size,
                              hipStream_t stream)
{
    const float* seq     = (const float*)d_in[0];
    const float* pair    = (const float*)d_in[1];
    const float* ln_p_w  = (const float*)d_in[2];
    const float* ln_p_b  = (const float*)d_in[3];
    const float* pool_w  = (const float*)d_in[4];
    const float* pool_b  = (const float*)d_in[5];
    const float* proj_w  = (const float*)d_in[6];
    const float* proj_b  = (const float*)d_in[7];
    const float* gate_ps = (const float*)d_in[8];
    const float* ln_s_w  = (const float*)d_in[9];
    const float* ln_s_b  = (const float*)d_in[10];
    const float* w1      = (const float*)d_in[11];
    const float* b1      = (const float*)d_in[12];
    const float* w2      = (const float*)d_in[13];
    const float* b2      = (const float*)d_in[14];
    const float* gate_sp = (const float*)d_in[15];

    float* seq_out  = (float*)d_out;
    float* pair_out = seq_out + 2 * 512 * 256;

    float* hi_ws = (float*)d_ws;                         // 1024*128 f32
    float* hj_ws = hi_ws + 1024 * 128;                   // 1024*128 f32
    unsigned short* w2t = (unsigned short*)(hj_ws + 1024 * 128);  // 128*128 bf16

    hipLaunchKernelGGL(k1_pair2seq, dim3(1024), dim3(512), 0, stream,
        seq, pair, ln_p_w, ln_p_b, pool_w, pool_b, proj_w, proj_b,
        gate_ps, ln_s_w, ln_s_b, w1, b1, w2, seq_out, hi_ws, hj_ws, w2t);
    hipLaunchKernelGGL(k2_seq2pair, dim3(4096), dim3(512), 0, stream,
        pair, hi_ws, hj_ws, w2t, b2, gate_sp, pair_out);
}